// Round 2
// baseline (266.089 us; speedup 1.0000x reference)
//
#include <hip/hip_runtime.h>
#include <math.h>

#define NTOK 16384
#define HDIM 2048
#define NEXP 64
#define TOPK 6
#define TB   32          // tokens per block
#define CH   64          // h per round
#define NR   (HDIM / CH) // 32 rounds
#define XPAD 68          // xs row stride in floats (272 B, 16B-aligned, spreads banks)

// LDS: double-buffered stage tiles; logits overlay the same memory after the loop.
union SMem {
    struct {
        float xs[2][TB][XPAD];    // 17408 B, unswizzled (padded rows)
        float ws[2][NEXP][CH];    // 32768 B, XOR-swizzled: col' = col ^ (((row>>2)&7)<<2)
    } s;
    float lg[TB][NEXP + 1];       // 8320 B logits, used after final sync
};

__device__ __forceinline__ void load_tiles(const float* __restrict__ x,
                                           const float* __restrict__ w,
                                           int tbase, int hbase, int tid,
                                           float4 xr[2], float4 wr[4]) {
    #pragma unroll
    for (int k = 0; k < 2; ++k) {           // x: 32 rows x 16 float4
        const int f = tid + 256 * k;
        xr[k] = *(const float4*)&x[(size_t)(tbase + (f >> 4)) * HDIM + hbase + 4 * (f & 15)];
    }
    #pragma unroll
    for (int k = 0; k < 4; ++k) {           // w: 64 rows x 16 float4
        const int f = tid + 256 * k;
        wr[k] = *(const float4*)&w[(size_t)(f >> 4) * HDIM + hbase + 4 * (f & 15)];
    }
}

__device__ __forceinline__ void write_tiles(float* xsb, float* wsb, int tid,
                                            const float4 xr[2], const float4 wr[4]) {
    #pragma unroll
    for (int k = 0; k < 2; ++k) {
        const int f = tid + 256 * k;
        *(float4*)&xsb[(f >> 4) * XPAD + 4 * (f & 15)] = xr[k];
    }
    #pragma unroll
    for (int k = 0; k < 4; ++k) {
        const int f = tid + 256 * k;
        const int row = f >> 4, slot = f & 15;
        *(float4*)&wsb[row * CH + 4 * (slot ^ ((row >> 2) & 7))] = wr[k];
    }
}

#define FMA4(A, X, W)                      \
    A.x = fmaf(X.x, W.x, A.x);             \
    A.y = fmaf(X.y, W.y, A.y);             \
    A.z = fmaf(X.z, W.z, A.z);             \
    A.w = fmaf(X.w, W.w, A.w);

__global__ __launch_bounds__(256, 4) void moe_gate_kernel(
        const float* __restrict__ x,
        const float* __restrict__ w,
        float* __restrict__ out)
{
    __shared__ SMem sm;

    const int tid   = threadIdx.x;
    const int wv    = tid >> 6;        // wave 0..3 -> tokens 8*wv .. 8*wv+7
    const int lane  = tid & 63;
    const int tokg  = lane >> 4;       // 0..3 : token pair 2*tokg, 2*tokg+1 (within wave's 8)
    const int expg  = lane & 15;       // 0..15: experts 4*expg .. 4*expg+3
    const int kwb   = (expg & 7) << 4; // byte XOR key for swizzled ws reads (lane-const)
    const int tbase = blockIdx.x * TB;

    float4 acc[2][4];
    #pragma unroll
    for (int r = 0; r < 2; ++r)
        #pragma unroll
        for (int s = 0; s < 4; ++s)
            acc[r][s] = make_float4(0.f, 0.f, 0.f, 0.f);

    float4 xr[2], wr[4];

    // prologue: stage round 0
    load_tiles(x, w, tbase, 0, tid, xr, wr);
    write_tiles(&sm.s.xs[0][0][0], &sm.s.ws[0][0][0], tid, xr, wr);
    __syncthreads();

    for (int rd = 0; rd < NR; ++rd) {
        // issue next round's global loads (latency hides under compute)
        if (rd + 1 < NR) load_tiles(x, w, tbase, (rd + 1) * CH, tid, xr, wr);

        // compute current buffer: pure ds_read_b128 (const offsets) + v_fma
        {
            const int buf = rd & 1;
            const float* xrow = &sm.s.xs[buf][8 * wv + 2 * tokg][0];
            const char*  wrow = (const char*)&sm.s.ws[buf][4 * expg][0];
            #pragma unroll
            for (int b = 0; b < 16; ++b) {
                const char* wp = wrow + ((b << 4) ^ kwb);   // 1 XOR per step
                const float4 w0 = *(const float4*)(wp);
                const float4 w1 = *(const float4*)(wp + CH * 4);
                const float4 w2 = *(const float4*)(wp + CH * 8);
                const float4 w3 = *(const float4*)(wp + CH * 12);
                const float4 x0 = *(const float4*)(xrow + 4 * b);
                const float4 x1 = *(const float4*)(xrow + XPAD + 4 * b);
                FMA4(acc[0][0], x0, w0) FMA4(acc[0][1], x0, w1)
                FMA4(acc[0][2], x0, w2) FMA4(acc[0][3], x0, w3)
                FMA4(acc[1][0], x1, w0) FMA4(acc[1][1], x1, w1)
                FMA4(acc[1][2], x1, w2) FMA4(acc[1][3], x1, w3)
            }
        }

        // stage next round into the other buffer; one barrier per round
        if (rd + 1 < NR)
            write_tiles(&sm.s.xs[(rd + 1) & 1][0][0], &sm.s.ws[(rd + 1) & 1][0][0], tid, xr, wr);
        __syncthreads();
    }

    // combine partials (SSE hsum order, identical to R1) -> logits LDS (overlay)
    #pragma unroll
    for (int r = 0; r < 2; ++r)
        #pragma unroll
        for (int s = 0; s < 4; ++s) {
            const float4 a = acc[r][s];
            sm.lg[8 * wv + 2 * tokg + r][4 * expg + s] = (a.x + a.z) + (a.y + a.w);
        }
    __syncthreads();

    // per-token top-6 + softmax + renorm (identical to R1)
    if (tid < TB) {
        const int tok = tid;
        float val[TOPK];
        int   idx[TOPK];
        #pragma unroll
        for (int k = 0; k < TOPK; ++k) { val[k] = -3.0e38f; idx[k] = 0; }

        for (int e = 0; e < NEXP; ++e) {
            float cv = sm.lg[tok][e];
            int   ci = e;
            #pragma unroll
            for (int k = 0; k < TOPK; ++k) {
                if (cv > val[k]) {
                    const float tv = val[k]; const int ti = idx[k];
                    val[k] = cv; idx[k] = ci;
                    cv = tv; ci = ti;
                }
            }
        }

        const float m = val[0];
        float ex[TOPK];
        float s = 0.f;
        #pragma unroll
        for (int k = 0; k < TOPK; ++k) { ex[k] = expf(val[k] - m); s += ex[k]; }
        float p[TOPK];
        float d = 0.f;
        #pragma unroll
        for (int k = 0; k < TOPK; ++k) { p[k] = ex[k] / s; d += p[k]; }
        d += 1e-20f;

        const int tg = tbase + tok;
        float* oi = out;
        float* ow = out + (size_t)NTOK * TOPK;
        #pragma unroll
        for (int k = 0; k < TOPK; ++k) {
            oi[tg * TOPK + k] = (float)idx[k];
            ow[tg * TOPK + k] = p[k] / d;
        }
    }
}

extern "C" void kernel_launch(void* const* d_in, const int* in_sizes, int n_in,
                              void* d_out, int out_size, void* d_ws, size_t ws_size,
                              hipStream_t stream) {
    const float* x = (const float*)d_in[0];
    const float* w = (const float*)d_in[1];
    float* out = (float*)d_out;
    dim3 grid(NTOK / TB);   // 512 blocks -> 2 blocks/CU
    dim3 block(256);
    hipLaunchKernelGGL(moe_gate_kernel, grid, block, 0, stream, x, w, out);
}

// Round 3
// 200.563 us; speedup vs baseline: 1.3267x; 1.3267x over previous
//
#include <hip/hip_runtime.h>
#include <math.h>

#define NTOK 16384
#define HDIM 2048
#define NEXP 64
#define TOPK 6
#define TB   16          // tokens per block
#define CH   64          // h per chunk
#define NCH  (HDIM / CH) // 32 chunks
#define XPAD 68          // xs row stride (272 B: 16B-aligned, rows spread banks)

// Stage buffers and the j-partial logit buffer overlay the same LDS.
union SMem {
    struct {
        float wt[CH][NEXP];   // transposed W chunk: wt[h][e]  (16 KB)
        float xs[TB][XPAD];   // x chunk, padded rows          (4.25 KB)
    } s;
    float lgp[2][TB][4][NEXP]; // per-wave 4-lane partials     (32 KB)
};

__device__ __forceinline__ float fcomp(const float4 v, int j) {
    return j == 0 ? v.x : (j == 1 ? v.y : (j == 2 ? v.z : v.w));
}

#define FMA4S(A, S, W)                     \
    A.x = fmaf(S, W.x, A.x);               \
    A.y = fmaf(S, W.y, A.y);               \
    A.z = fmaf(S, W.z, A.z);               \
    A.w = fmaf(S, W.w, A.w);

__global__ __launch_bounds__(128) void moe_gate_kernel(
        const float* __restrict__ x,
        const float* __restrict__ w,
        float* __restrict__ out)
{
    __shared__ SMem sm;

    const int tid   = threadIdx.x;
    const int wv    = tid >> 6;       // 0/1: h-half owner
    const int lane  = tid & 63;
    const int q     = lane >> 4;      // token quad: tokens 4q..4q+3
    const int eg    = lane & 15;      // experts 4eg..4eg+3
    const int tbase = blockIdx.x * TB;

    // staging roles
    const int wr    = tid >> 1;       // W source row (expert) 0..63
    const int whalf = tid & 1;        // which 8 float4 slots of that row
    const int xslot = tid & 15;       // x float4 slot 0..15
    const int xrow  = tid >> 4;       // x row base 0..7 (+8*k)

    // acc[r][j]: float4 over experts s for (token 4q+r, partial lane j=h%4)
    float4 acc[4][4];
    #pragma unroll
    for (int r = 0; r < 4; ++r)
        #pragma unroll
        for (int j = 0; j < 4; ++j)
            acc[r][j] = make_float4(0.f, 0.f, 0.f, 0.f);

    // ---- prologue: stage chunk 0 ----
    {
        #pragma unroll
        for (int m = 0; m < 8; ++m) {
            const float4 v = *(const float4*)&w[(size_t)wr * HDIM + 4 * (8 * whalf + m)];
            const int hrow = 4 * (8 * whalf + m);
            sm.s.wt[hrow + 0][wr] = v.x;
            sm.s.wt[hrow + 1][wr] = v.y;
            sm.s.wt[hrow + 2][wr] = v.z;
            sm.s.wt[hrow + 3][wr] = v.w;
        }
        #pragma unroll
        for (int k = 0; k < 2; ++k) {
            const float4 v = *(const float4*)&x[(size_t)(tbase + xrow + 8 * k) * HDIM + 4 * xslot];
            *(float4*)&sm.s.xs[xrow + 8 * k][4 * xslot] = v;
        }
    }
    __syncthreads();

    for (int ck = 0; ck < NCH; ++ck) {
        // prefetch next chunk into registers (latency hides under compute)
        float4 pw0, pw1, pw2, pw3, pw4, pw5, pw6, pw7, px0, px1;
        if (ck + 1 < NCH) {
            const size_t wb = (size_t)wr * HDIM + (size_t)(ck + 1) * CH + 32 * whalf;
            pw0 = *(const float4*)&w[wb +  0]; pw1 = *(const float4*)&w[wb +  4];
            pw2 = *(const float4*)&w[wb +  8]; pw3 = *(const float4*)&w[wb + 12];
            pw4 = *(const float4*)&w[wb + 16]; pw5 = *(const float4*)&w[wb + 20];
            pw6 = *(const float4*)&w[wb + 24]; pw7 = *(const float4*)&w[wb + 28];
            px0 = *(const float4*)&x[(size_t)(tbase + xrow) * HDIM + (size_t)(ck + 1) * CH + 4 * xslot];
            px1 = *(const float4*)&x[(size_t)(tbase + xrow + 8) * HDIM + (size_t)(ck + 1) * CH + 4 * xslot];
        }

        // compute this wave's h-half: 8 steps of 4 h each
        #pragma unroll
        for (int st = 0; st < 8; ++st) {
            const int h4 = 8 * wv + st;           // float4-slot index 0..15
            float4 xv[4], wj[4];
            #pragma unroll
            for (int r = 0; r < 4; ++r)
                xv[r] = *(const float4*)&sm.s.xs[4 * q + r][4 * h4];
            #pragma unroll
            for (int j = 0; j < 4; ++j)
                wj[j] = *(const float4*)&sm.s.wt[4 * h4 + j][4 * eg];
            #pragma unroll
            for (int r = 0; r < 4; ++r)
                #pragma unroll
                for (int j = 0; j < 4; ++j) {
                    const float sx = fcomp(xv[r], j);
                    FMA4S(acc[r][j], sx, wj[j])
                }
        }
        __syncthreads();

        if (ck + 1 < NCH) {
            // write prefetched regs -> LDS (transpose W; 2-way banks, free)
            const int hb0 = 32 * whalf;
            #pragma unroll
            for (int m = 0; m < 8; ++m) {
                const float4 v = (m == 0) ? pw0 : (m == 1) ? pw1 : (m == 2) ? pw2 : (m == 3) ? pw3
                               : (m == 4) ? pw4 : (m == 5) ? pw5 : (m == 6) ? pw6 : pw7;
                const int hrow = hb0 + 4 * m;
                sm.s.wt[hrow + 0][wr] = v.x;
                sm.s.wt[hrow + 1][wr] = v.y;
                sm.s.wt[hrow + 2][wr] = v.z;
                sm.s.wt[hrow + 3][wr] = v.w;
            }
            *(float4*)&sm.s.xs[xrow][4 * xslot]     = px0;
            *(float4*)&sm.s.xs[xrow + 8][4 * xslot] = px1;
        }
        __syncthreads();
    }

    // ---- write per-wave j-partials into overlay buffer ----
    #pragma unroll
    for (int r = 0; r < 4; ++r)
        #pragma unroll
        for (int j = 0; j < 4; ++j)
            *(float4*)&sm.lgp[wv][4 * q + r][j][4 * eg] = acc[r][j];
    __syncthreads();

    // ---- per-token top-6 + softmax + renorm (same insertion/softmax as R1) ----
    if (tid < TB) {
        float val[TOPK];
        int   idx[TOPK];
        #pragma unroll
        for (int k = 0; k < TOPK; ++k) { val[k] = -3.0e38f; idx[k] = 0; }

        for (int e = 0; e < NEXP; ++e) {
            // lane-wise cross-wave combine, then R1's (0+2)+(1+3) order
            const float J0 = sm.lgp[0][tid][0][e] + sm.lgp[1][tid][0][e];
            const float J1 = sm.lgp[0][tid][1][e] + sm.lgp[1][tid][1][e];
            const float J2 = sm.lgp[0][tid][2][e] + sm.lgp[1][tid][2][e];
            const float J3 = sm.lgp[0][tid][3][e] + sm.lgp[1][tid][3][e];
            float cv = (J0 + J2) + (J1 + J3);
            int   ci = e;
            #pragma unroll
            for (int k = 0; k < TOPK; ++k) {
                if (cv > val[k]) {                 // strict >: lowest index wins ties
                    const float tv = val[k]; const int ti = idx[k];
                    val[k] = cv; idx[k] = ci;
                    cv = tv; ci = ti;
                }
            }
        }

        const float m = val[0];
        float ex[TOPK];
        float s = 0.f;
        #pragma unroll
        for (int k = 0; k < TOPK; ++k) { ex[k] = expf(val[k] - m); s += ex[k]; }
        float p[TOPK];
        float d = 0.f;
        #pragma unroll
        for (int k = 0; k < TOPK; ++k) { p[k] = ex[k] / s; d += p[k]; }
        d += 1e-20f;

        const int tg = tbase + tid;
        float* oi = out;                           // idx chunk   [NTOK*TOPK]
        float* ow = out + (size_t)NTOK * TOPK;     // weight chunk
        #pragma unroll
        for (int k = 0; k < TOPK; ++k) {
            oi[tg * TOPK + k] = (float)idx[k];
            ow[tg * TOPK + k] = p[k] / d;
        }
    }
}

extern "C" void kernel_launch(void* const* d_in, const int* in_sizes, int n_in,
                              void* d_out, int out_size, void* d_ws, size_t ws_size,
                              hipStream_t stream) {
    const float* x = (const float*)d_in[0];
    const float* w = (const float*)d_in[1];
    float* out = (float*)d_out;
    dim3 grid(NTOK / TB);   // 1024 blocks -> 4 blocks/CU
    dim3 block(128);        // 2 waves: wave = h-half
    hipLaunchKernelGGL(moe_gate_kernel, grid, block, 0, stream, x, w, out);
}

// Round 4
// 117.299 us; speedup vs baseline: 2.2685x; 1.7098x over previous
//
#include <hip/hip_runtime.h>
#include <math.h>

#define NTOK 16384
#define HDIM 2048
#define NEXP 64
#define TOPK 6
#define TB   32          // tokens per block
#define CH   64          // h per chunk
#define NCH  (HDIM / CH) // 32 chunks
#define XPAD 68          // xs row stride in floats

// Stage buffers and epilogue combine buffers overlay the same LDS (union).
union SMem {
    struct {
        float ws[NEXP][CH];       // 16 KB, float4-slot XOR-swizzled: slot' = slot ^ ((row>>2)&7)
        float xs[TB][XPAD];       // 8.5 KB, padded rows
    } s;
    struct {
        float4 h1[2][16][16][4];  // 32 KB: [ts][tok16][eg][s] = half-1 acc, lane-identical layout
        float  lg[TB][NEXP + 1];  // 8.3 KB logits
    } e;
};

#define FMA4(A, X, W)                      \
    A.x = fmaf(X.x, W.x, A.x);             \
    A.y = fmaf(X.y, W.y, A.y);             \
    A.z = fmaf(X.z, W.z, A.z);             \
    A.w = fmaf(X.w, W.w, A.w);

__global__ __launch_bounds__(256, 2) void moe_gate_kernel(
        const float* __restrict__ x,
        const float* __restrict__ w,
        float* __restrict__ out)
{
    __shared__ SMem sm;

    const int tid   = threadIdx.x;
    const int wv    = tid >> 6;
    const int lane  = tid & 63;
    const int hh    = wv >> 1;        // h-half: waves 0,1 -> [0,32); waves 2,3 -> [32,64)
    const int ts    = wv & 1;         // token sub-block: tokens 16*ts .. 16*ts+15
    const int q     = lane >> 4;      // token quad within sub-block
    const int eg    = lane & 15;      // experts 4*eg .. 4*eg+3
    const int tbase = blockIdx.x * TB;
    const int tokL  = 16 * ts + 4 * q;

    // acc[r][s]: float4 over j = h%4 partial lanes for (token tokL+r, expert 4*eg+s)
    float4 acc[4][4];
    #pragma unroll
    for (int r = 0; r < 4; ++r)
        #pragma unroll
        for (int s = 0; s < 4; ++s)
            acc[r][s] = make_float4(0.f, 0.f, 0.f, 0.f);

    for (int ck = 0; ck < NCH; ++ck) {
        // ---- stage chunk: coalesced global float4 -> LDS b128 (R1 pattern) ----
        #pragma unroll
        for (int k = 0; k < 2; ++k) {            // x: 32 rows x 16 float4
            const int f = tid + 256 * k;
            const int row = f >> 4, slot = f & 15;
            *(float4*)&sm.s.xs[row][4 * slot] =
                *(const float4*)&x[(size_t)(tbase + row) * HDIM + ck * CH + 4 * slot];
        }
        #pragma unroll
        for (int k = 0; k < 4; ++k) {            // w: 64 rows x 16 float4, swizzled
            const int f = tid + 256 * k;
            const int row = f >> 4, slot = f & 15;
            *(float4*)&sm.s.ws[row][4 * (slot ^ ((row >> 2) & 7))] =
                *(const float4*)&w[(size_t)row * HDIM + ck * CH + 4 * slot];
        }
        __syncthreads();

        // ---- compute this wave's h-half: 8 steps x 4 h (R1 inner loop) ----
        {
            const float* xb = &sm.s.xs[tokL][0];
            const char*  wb = (const char*)&sm.s.ws[4 * eg][0];
            const int    kx = (eg & 7) << 4;     // byte XOR key (lane-const)
            #pragma unroll
            for (int st = 0; st < 8; ++st) {
                const int slot  = 8 * hh + st;
                const int sbyte = (slot << 4) ^ kx;
                const float4 w0 = *(const float4*)(wb + sbyte);
                const float4 w1 = *(const float4*)(wb + sbyte + CH * 4);
                const float4 w2 = *(const float4*)(wb + sbyte + CH * 8);
                const float4 w3 = *(const float4*)(wb + sbyte + CH * 12);
                const float4 x0 = *(const float4*)(xb + 4 * slot);
                const float4 x1 = *(const float4*)(xb + XPAD + 4 * slot);
                const float4 x2 = *(const float4*)(xb + 2 * XPAD + 4 * slot);
                const float4 x3 = *(const float4*)(xb + 3 * XPAD + 4 * slot);
                FMA4(acc[0][0], x0, w0) FMA4(acc[0][1], x0, w1)
                FMA4(acc[0][2], x0, w2) FMA4(acc[0][3], x0, w3)
                FMA4(acc[1][0], x1, w0) FMA4(acc[1][1], x1, w1)
                FMA4(acc[1][2], x1, w2) FMA4(acc[1][3], x1, w3)
                FMA4(acc[2][0], x2, w0) FMA4(acc[2][1], x2, w1)
                FMA4(acc[2][2], x2, w2) FMA4(acc[2][3], x2, w3)
                FMA4(acc[3][0], x3, w0) FMA4(acc[3][1], x3, w1)
                FMA4(acc[3][2], x3, w2) FMA4(acc[3][3], x3, w3)
            }
        }
        __syncthreads();
    }

    // ---- cross-half combine: half-1 stores acc verbatim; half-0 adds lane-wise ----
    if (hh == 1) {
        #pragma unroll
        for (int r = 0; r < 4; ++r)
            #pragma unroll
            for (int s = 0; s < 4; ++s)
                sm.e.h1[ts][4 * q + r][eg][s] = acc[r][s];
    }
    __syncthreads();
    if (hh == 0) {
        #pragma unroll
        for (int r = 0; r < 4; ++r)
            #pragma unroll
            for (int s = 0; s < 4; ++s) {
                const float4 o  = sm.e.h1[ts][4 * q + r][eg][s];
                const float  J0 = acc[r][s].x + o.x;
                const float  J1 = acc[r][s].y + o.y;
                const float  J2 = acc[r][s].z + o.z;
                const float  J3 = acc[r][s].w + o.w;
                sm.e.lg[tokL + r][4 * eg + s] = (J0 + J2) + (J1 + J3);
            }
    }
    __syncthreads();

    // ---- per-token top-6 + softmax + renorm (identical numerics to R1) ----
    if (tid < TB) {
        float val[TOPK];
        int   idx[TOPK];
        #pragma unroll
        for (int k = 0; k < TOPK; ++k) { val[k] = -3.0e38f; idx[k] = 0; }

        for (int e = 0; e < NEXP; ++e) {
            float cv = sm.e.lg[tid][e];
            int   ci = e;
            #pragma unroll
            for (int k = 0; k < TOPK; ++k) {
                if (cv > val[k]) {                 // strict >: lowest index wins ties
                    const float tv = val[k]; const int ti = idx[k];
                    val[k] = cv; idx[k] = ci;
                    cv = tv; ci = ti;
                }
            }
        }

        const float m = val[0];
        float ex[TOPK];
        float s = 0.f;
        #pragma unroll
        for (int k = 0; k < TOPK; ++k) { ex[k] = expf(val[k] - m); s += ex[k]; }
        float p[TOPK];
        float d = 0.f;
        #pragma unroll
        for (int k = 0; k < TOPK; ++k) { p[k] = ex[k] / s; d += p[k]; }
        d += 1e-20f;

        const int tg = tbase + tid;
        float* oi = out;                           // idx chunk   [NTOK*TOPK]
        float* ow = out + (size_t)NTOK * TOPK;     // weight chunk
        #pragma unroll
        for (int k = 0; k < TOPK; ++k) {
            oi[tg * TOPK + k] = (float)idx[k];
            ow[tg * TOPK + k] = p[k] / d;
        }
    }
}

extern "C" void kernel_launch(void* const* d_in, const int* in_sizes, int n_in,
                              void* d_out, int out_size, void* d_ws, size_t ws_size,
                              hipStream_t stream) {
    const float* x = (const float*)d_in[0];
    const float* w = (const float*)d_in[1];
    float* out = (float*)d_out;
    dim3 grid(NTOK / TB);   // 512 blocks -> 2 blocks/CU
    dim3 block(256);        // 4 waves: (h-half, token-sub) = (wv>>1, wv&1)
    hipLaunchKernelGGL(moe_gate_kernel, grid, block, 0, stream, x, w, out);
}